// Round 1
// baseline (291.663 us; speedup 1.0000x reference)
//
#include <hip/hip_runtime.h>
#include <math.h>

#define N_NODES 4096
#define DIM 256
#define HEADS 4
#define HDIM 64
#define NEDGE 131072
#define MAXNBR 256
#define MASK_WORDS 128   // 4096 / 32

// ---------------- mask / CSR construction ----------------

__global__ void zero_words_kernel(unsigned int* p, int n) {
    int t = blockIdx.x * blockDim.x + threadIdx.x;
    if (t < n) p[t] = 0u;
}

__global__ void build_mask_kernel(const int* __restrict__ eidx, unsigned int* __restrict__ mask) {
    int t = blockIdx.x * blockDim.x + threadIdx.x;
    if (t < NEDGE) {
        int s = eidx[t];
        int d = eidx[NEDGE + t];
        atomicOr(&mask[s * MASK_WORDS + (d >> 5)], 1u << (d & 31));
        atomicOr(&mask[d * MASK_WORDS + (s >> 5)], 1u << (s & 31));
    } else if (t < NEDGE + N_NODES) {
        int i = t - NEDGE;
        atomicOr(&mask[i * MASK_WORDS + (i >> 5)], 1u << (i & 31));
    }
}

__global__ void extract_csr_kernel(const unsigned int* __restrict__ mask,
                                   int* __restrict__ nnz, int* __restrict__ cols) {
    int i = blockIdx.x * blockDim.x + threadIdx.x;
    if (i >= N_NODES) return;
    const unsigned int* row = mask + i * MASK_WORDS;
    int c = 0;
    for (int w = 0; w < MASK_WORDS; ++w) {
        unsigned int bits = row[w];
        while (bits) {
            int b = __ffs(bits) - 1;
            if (c < MAXNBR) cols[i * MAXNBR + c] = w * 32 + b;
            ++c;
            bits &= bits - 1u;
        }
    }
    nnz[i] = (c > MAXNBR) ? MAXNBR : c;
}

// ---------------- fp32 tiled GEMM:  C[M][Nc] = A[M][K] * B[Nc][K]^T + bias (+resid) ----

// BM=BN=64, BK=16, 256 threads, 4x4 per thread
__global__ __launch_bounds__(256)
void gemm_bt_kernel(const float* __restrict__ A, const float* __restrict__ B,
                    const float* __restrict__ bias, const float* __restrict__ resid,
                    float* __restrict__ C, int M, int Nc, int K) {
    __shared__ float As[16][65];
    __shared__ float Bs[16][65];
    const int tid = threadIdx.x;
    const int block_row = blockIdx.y * 64;
    const int block_col = blockIdx.x * 64;
    const int tx = tid & 15;        // 0..15 (cols)
    const int ty = tid >> 4;        // 0..15 (rows)

    const int l_row = tid >> 2;           // 0..63
    const int l_col = (tid & 3) * 4;      // 0,4,8,12

    float acc[4][4] = {};

    for (int k0 = 0; k0 < K; k0 += 16) {
        float4 av = *(const float4*)&A[(size_t)(block_row + l_row) * K + k0 + l_col];
        float4 bv = *(const float4*)&B[(size_t)(block_col + l_row) * K + k0 + l_col];
        __syncthreads();
        As[l_col + 0][l_row] = av.x;
        As[l_col + 1][l_row] = av.y;
        As[l_col + 2][l_row] = av.z;
        As[l_col + 3][l_row] = av.w;
        Bs[l_col + 0][l_row] = bv.x;
        Bs[l_col + 1][l_row] = bv.y;
        Bs[l_col + 2][l_row] = bv.z;
        Bs[l_col + 3][l_row] = bv.w;
        __syncthreads();
#pragma unroll
        for (int kk = 0; kk < 16; ++kk) {
            float ar[4], br[4];
#pragma unroll
            for (int i = 0; i < 4; ++i) ar[i] = As[kk][ty * 4 + i];
#pragma unroll
            for (int j = 0; j < 4; ++j) br[j] = Bs[kk][tx * 4 + j];
#pragma unroll
            for (int i = 0; i < 4; ++i)
#pragma unroll
                for (int j = 0; j < 4; ++j)
                    acc[i][j] += ar[i] * br[j];
        }
    }

#pragma unroll
    for (int i = 0; i < 4; ++i) {
        int r = block_row + ty * 4 + i;
#pragma unroll
        for (int j = 0; j < 4; ++j) {
            int c = block_col + tx * 4 + j;
            float v = acc[i][j] + bias[c];
            if (resid) v += resid[(size_t)r * Nc + c];
            C[(size_t)r * Nc + c] = v;
        }
    }
}

// ---------------- sparse masked attention ----------------
// One block (256 thr) per query row i; wave w = head h. qkv layout [N][3*DIM].

__global__ __launch_bounds__(256)
void attn_sparse_kernel(const float* __restrict__ qkv, const int* __restrict__ cols,
                        const int* __restrict__ nnz, float* __restrict__ ctx) {
    __shared__ float q_s[HEADS][HDIM];
    __shared__ float sc[HEADS][MAXNBR];
    __shared__ int cols_s[MAXNBR];

    const int wave = threadIdx.x >> 6;   // head
    const int lane = threadIdx.x & 63;
    const int i = blockIdx.x;
    const int h = wave;

    q_s[wave][lane] = qkv[(size_t)i * 768 + h * HDIM + lane];
    cols_s[threadIdx.x] = cols[(size_t)i * MAXNBR + threadIdx.x];
    int count = nnz[i];
    if (count > MAXNBR) count = MAXNBR;
    __syncthreads();

    // phase 1: scores (lane t handles neighbors t, t+64, t+128, t+192)
    float m_local = -1e30f;
    float sv[4];
#pragma unroll
    for (int r = 0; r < 4; ++r) {
        int t = lane + r * 64;
        float s = -1e30f;
        if (t < count) {
            int j = cols_s[t];
            const float* kp = qkv + (size_t)j * 768 + DIM + h * HDIM;
            float a = 0.f;
#pragma unroll
            for (int d = 0; d < HDIM; d += 4) {
                float4 qv = *(const float4*)&q_s[wave][d];
                float4 kv = *(const float4*)&kp[d];
                a += qv.x * kv.x + qv.y * kv.y + qv.z * kv.z + qv.w * kv.w;
            }
            s = a * 0.125f;   // 1/sqrt(64)
        }
        sv[r] = s;
        m_local = fmaxf(m_local, s);
    }
#pragma unroll
    for (int off = 32; off > 0; off >>= 1)
        m_local = fmaxf(m_local, __shfl_xor(m_local, off, 64));

    float sum_local = 0.f;
#pragma unroll
    for (int r = 0; r < 4; ++r) {
        int t = lane + r * 64;
        float e = (t < count) ? expf(sv[r] - m_local) : 0.f;
        sum_local += e;
        sc[wave][t] = e;
    }
#pragma unroll
    for (int off = 32; off > 0; off >>= 1)
        sum_local += __shfl_xor(sum_local, off, 64);
    float inv = 1.0f / sum_local;
    __syncthreads();

    // phase 2: lane = output dim d
    float acc = 0.f;
    for (int t = 0; t < count; ++t) {
        int j = cols_s[t];
        float p = sc[wave][t];
        acc += p * qkv[(size_t)j * 768 + 2 * DIM + h * HDIM + lane];
    }
    ctx[(size_t)i * DIM + h * HDIM + lane] = acc * inv;
}

// ---------------- LayerNorm ----------------
// wave per row, lane holds float4 (4 consecutive elems)

__global__ __launch_bounds__(256)
void ln_kernel(const float* __restrict__ y, const float* __restrict__ gamma,
               const float* __restrict__ beta, float* __restrict__ out) {
    const int wave = threadIdx.x >> 6;
    const int lane = threadIdx.x & 63;
    const int i = blockIdx.x * 4 + wave;
    float4 v = ((const float4*)(y + (size_t)i * DIM))[lane];
    float s = v.x + v.y + v.z + v.w;
    float ss = v.x * v.x + v.y * v.y + v.z * v.z + v.w * v.w;
#pragma unroll
    for (int off = 32; off > 0; off >>= 1) {
        s += __shfl_xor(s, off, 64);
        ss += __shfl_xor(ss, off, 64);
    }
    float mean = s * (1.f / 256.f);
    float var = ss * (1.f / 256.f) - mean * mean;
    float rstd = rsqrtf(var + 1e-5f);
    float4 g = ((const float4*)gamma)[lane];
    float4 b = ((const float4*)beta)[lane];
    float4 o;
    o.x = (v.x - mean) * rstd * g.x + b.x;
    o.y = (v.y - mean) * rstd * g.y + b.y;
    o.z = (v.z - mean) * rstd * g.z + b.z;
    o.w = (v.w - mean) * rstd * g.w + b.w;
    ((float4*)(out + (size_t)i * DIM))[lane] = o;
}

// ---------------- launch ----------------

extern "C" void kernel_launch(void* const* d_in, const int* in_sizes, int n_in,
                              void* d_out, int out_size, void* d_ws, size_t ws_size,
                              hipStream_t stream) {
    const float* x      = (const float*)d_in[0];
    const int*   eidx   = (const int*)d_in[1];
    const float* w_in   = (const float*)d_in[2];
    const float* b_in   = (const float*)d_in[3];
    const float* w_out  = (const float*)d_in[4];
    const float* b_out  = (const float*)d_in[5];
    const float* w_p    = (const float*)d_in[6];
    const float* b_p    = (const float*)d_in[7];
    const float* gamma  = (const float*)d_in[8];
    const float* beta   = (const float*)d_in[9];
    float* out = (float*)d_out;

    char* ws = (char*)d_ws;
    unsigned int* mask = (unsigned int*)(ws);                       // 2 MB
    int*   nnz  = (int*)  (ws + 2097152);                           // 16 KB
    int*   cols = (int*)  (ws + 2097152 + 16384);                   // 4 MB
    float* qkv  = (float*)(ws + 2097152 + 16384 + 4194304);         // 12 MB
    float* ctx  = (float*)(ws + 2097152 + 16384 + 4194304 + 12582912);        // 4 MB
    float* att  = (float*)(ws + 2097152 + 16384 + 4194304 + 12582912 + 4194304);  // 4 MB
    float* ybuf = (float*)(ws + 2097152 + 16384 + 4194304 + 12582912 + 2 * 4194304); // 4 MB

    // 1. zero mask
    {
        int nwords = N_NODES * MASK_WORDS;
        zero_words_kernel<<<(nwords + 511) / 512, 512, 0, stream>>>(mask, nwords);
    }
    // 2. scatter edges + diag
    {
        int total = NEDGE + N_NODES;
        build_mask_kernel<<<(total + 255) / 256, 256, 0, stream>>>(eidx, mask);
    }
    // 3. extract CSR
    extract_csr_kernel<<<N_NODES / 256, 256, 0, stream>>>(mask, nnz, cols);
    // 4. qkv = x @ w_in^T + b_in   [4096 x 768]
    {
        dim3 grid(768 / 64, N_NODES / 64);
        gemm_bt_kernel<<<grid, 256, 0, stream>>>(x, w_in, b_in, nullptr, qkv,
                                                 N_NODES, 768, DIM);
    }
    // 5. sparse attention -> ctx [4096 x 256]
    attn_sparse_kernel<<<N_NODES, 256, 0, stream>>>(qkv, cols, nnz, ctx);
    // 6. att = ctx @ w_out^T + b_out
    {
        dim3 grid(DIM / 64, N_NODES / 64);
        gemm_bt_kernel<<<grid, 256, 0, stream>>>(ctx, w_out, b_out, nullptr, att,
                                                 N_NODES, DIM, DIM);
    }
    // 7. y = att @ w_p^T + b_p + x
    {
        dim3 grid(DIM / 64, N_NODES / 64);
        gemm_bt_kernel<<<grid, 256, 0, stream>>>(att, w_p, b_p, x, ybuf,
                                                 N_NODES, DIM, DIM);
    }
    // 8. LayerNorm -> out
    ln_kernel<<<N_NODES / 4, 256, 0, stream>>>(ybuf, gamma, beta, out);
}

// Round 3
// 176.014 us; speedup vs baseline: 1.6570x; 1.6570x over previous
//
#include <hip/hip_runtime.h>
#include <math.h>

#define N_NODES 4096
#define DIM 256
#define HEADS 4
#define HDIM 64
#define NEDGE 131072
#define MAXNBR 256
#define MASK_WORDS 128   // 4096 / 32

typedef __attribute__((ext_vector_type(8))) short short8;
typedef __attribute__((ext_vector_type(4))) float float4v;

__device__ inline unsigned short f2b(float f) {   // fp32 -> bf16 RNE
    unsigned u = __float_as_uint(f);
    unsigned r = u + 0x7fffu + ((u >> 16) & 1u);
    return (unsigned short)(r >> 16);
}
__device__ inline float b2f(unsigned short s) { return __uint_as_float(((unsigned)s) << 16); }
__device__ inline float bl(unsigned u) { return __uint_as_float(u << 16); }      // low bf16 of packed word
__device__ inline float bh(unsigned u) { return __uint_as_float(u & 0xffff0000u); } // high bf16

// ---------------- fp32 -> bf16 conversion ----------------
__global__ void f32_to_bf16_kernel(const float* __restrict__ src,
                                   unsigned short* __restrict__ dst, int n) {
    int t = (blockIdx.x * blockDim.x + threadIdx.x) * 4;
    if (t >= n) return;
    float4 v = *(const float4*)&src[t];
    ushort4 o;
    o.x = f2b(v.x); o.y = f2b(v.y); o.z = f2b(v.z); o.w = f2b(v.w);
    *(ushort4*)&dst[t] = o;
}

// ---------------- mask / CSR construction ----------------
__global__ void zero_words_kernel(unsigned int* p, int n) {
    int t = blockIdx.x * blockDim.x + threadIdx.x;
    if (t < n) p[t] = 0u;
}

__global__ void build_mask_kernel(const int* __restrict__ eidx, unsigned int* __restrict__ mask) {
    int t = blockIdx.x * blockDim.x + threadIdx.x;
    if (t < NEDGE) {
        int s = eidx[t];
        int d = eidx[NEDGE + t];
        atomicOr(&mask[s * MASK_WORDS + (d >> 5)], 1u << (d & 31));
        atomicOr(&mask[d * MASK_WORDS + (s >> 5)], 1u << (s & 31));
    } else if (t < NEDGE + N_NODES) {
        int i = t - NEDGE;
        atomicOr(&mask[i * MASK_WORDS + (i >> 5)], 1u << (i & 31));
    }
}

// wave-per-row CSR extraction: lane handles 2 words, prefix-scan offsets
__global__ __launch_bounds__(256)
void extract_csr_kernel(const unsigned int* __restrict__ mask,
                        int* __restrict__ nnz, int* __restrict__ cols) {
    const int wave = threadIdx.x >> 6;
    const int lane = threadIdx.x & 63;
    const int i = blockIdx.x * 4 + wave;
    const unsigned int* row = mask + (size_t)i * MASK_WORDS;
    unsigned w0 = row[lane * 2];
    unsigned w1 = row[lane * 2 + 1];
    int cnt = __popc(w0) + __popc(w1);
    int incl = cnt;
#pragma unroll
    for (int off = 1; off < 64; off <<= 1) {
        int v = __shfl_up(incl, off, 64);
        if (lane >= off) incl += v;
    }
    int c = incl - cnt;
    int total = __shfl(incl, 63, 64);
    while (w0) {
        int b = __ffs(w0) - 1;
        if (c < MAXNBR) cols[(size_t)i * MAXNBR + c] = lane * 64 + b;
        ++c; w0 &= w0 - 1u;
    }
    while (w1) {
        int b = __ffs(w1) - 1;
        if (c < MAXNBR) cols[(size_t)i * MAXNBR + c] = lane * 64 + 32 + b;
        ++c; w1 &= w1 - 1u;
    }
    if (lane == 0) nnz[i] = total > MAXNBR ? MAXNBR : total;
}

// ---------------- bf16 MFMA GEMM:  C[M][Nc] = A[M][K] x B[Nc][K]^T + bias (+resid) ----
// BM=BN=128, BK=64, 256 threads = 4 waves (2x2 of 64x64), mfma_f32_16x16x32_bf16.
// LDS tiles XOR-swizzled (chunk ^= row&7) so ds_read_b128 phases hit distinct banks.
template <bool OUT_BF16>
__global__ __launch_bounds__(256)
void mfma_gemm_bt(const unsigned short* __restrict__ A, const unsigned short* __restrict__ B,
                  const float* __restrict__ bias, const float* __restrict__ resid,
                  void* __restrict__ Cout, int M, int Nc, int K) {
    __shared__ unsigned short As[128 * 64];
    __shared__ unsigned short Bs[128 * 64];
    const int tid  = threadIdx.x;
    const int lane = tid & 63;
    const int wave = tid >> 6;
    const int wm = wave & 1;          // wave row (0..1)
    const int wn = wave >> 1;         // wave col (0..1)
    const int brow = blockIdx.y * 128;
    const int bcol = blockIdx.x * 128;

    float4v acc[16];
#pragma unroll
    for (int t = 0; t < 16; ++t) acc[t] = (float4v){0.f, 0.f, 0.f, 0.f};

    const int quad = lane >> 4;       // 0..3
    const int l16  = lane & 15;

    for (int k0 = 0; k0 < K; k0 += 64) {
        __syncthreads();
#pragma unroll
        for (int it = 0; it < 4; ++it) {
            int c = it * 256 + tid;
            int row = c >> 3;         // 0..127
            int col = c & 7;          // 16B chunk within 64-col (128B) row
            int sw  = col ^ (row & 7);
            uint4 va = *(const uint4*)&A[(size_t)(brow + row) * K + k0 + col * 8];
            uint4 vb = *(const uint4*)&B[(size_t)(bcol + row) * K + k0 + col * 8];
            *(uint4*)&As[row * 64 + sw * 8] = va;
            *(uint4*)&Bs[row * 64 + sw * 8] = vb;
        }
        __syncthreads();
#pragma unroll
        for (int kk = 0; kk < 2; ++kk) {
            short8 af[4], bf[4];
#pragma unroll
            for (int mt = 0; mt < 4; ++mt) {
                int row = wm * 64 + mt * 16 + l16;
                int sw = (kk * 4 + quad) ^ (row & 7);
                af[mt] = *(const short8*)&As[row * 64 + sw * 8];
            }
#pragma unroll
            for (int nt = 0; nt < 4; ++nt) {
                int row = wn * 64 + nt * 16 + l16;
                int sw = (kk * 4 + quad) ^ (row & 7);
                bf[nt] = *(const short8*)&Bs[row * 64 + sw * 8];
            }
#pragma unroll
            for (int mt = 0; mt < 4; ++mt)
#pragma unroll
                for (int nt = 0; nt < 4; ++nt)
                    acc[mt * 4 + nt] = __builtin_amdgcn_mfma_f32_16x16x32_bf16(
                        af[mt], bf[nt], acc[mt * 4 + nt], 0, 0, 0);
        }
    }

    // epilogue: D[row = quad*4+reg][col = l16]
#pragma unroll
    for (int mt = 0; mt < 4; ++mt) {
#pragma unroll
        for (int nt = 0; nt < 4; ++nt) {
            int colg = bcol + wn * 64 + nt * 16 + l16;
            float bsv = bias[colg];
#pragma unroll
            for (int reg = 0; reg < 4; ++reg) {
                int rowg = brow + wm * 64 + mt * 16 + quad * 4 + reg;
                float v = acc[mt * 4 + nt][reg] + bsv;
                if (resid) v += resid[(size_t)rowg * Nc + colg];
                if (OUT_BF16)
                    ((unsigned short*)Cout)[(size_t)rowg * Nc + colg] = f2b(v);
                else
                    ((float*)Cout)[(size_t)rowg * Nc + colg] = v;
            }
        }
    }
}

// ---------------- sparse masked attention (bf16 qkv) ----------------
// Block (256 thr) per query row i; wave = head. qkv_bf layout [N][768] bf16.
__global__ __launch_bounds__(256)
void attn_sparse_kernel(const unsigned short* __restrict__ qkv, const int* __restrict__ cols,
                        const int* __restrict__ nnz, unsigned short* __restrict__ ctx) {
    __shared__ float q_s[HEADS][HDIM];
    __shared__ float sc[HEADS][MAXNBR];
    __shared__ int cols_s[MAXNBR];

    const int wave = threadIdx.x >> 6;   // head
    const int lane = threadIdx.x & 63;
    const int i = blockIdx.x;
    const int h = wave;

    q_s[wave][lane] = b2f(qkv[(size_t)i * 768 + h * HDIM + lane]);
    cols_s[threadIdx.x] = cols[(size_t)i * MAXNBR + threadIdx.x];
    int count = nnz[i];
    if (count > MAXNBR) count = MAXNBR;
    __syncthreads();

    // phase 1: scores (lane t handles neighbors t, t+64, t+128, t+192)
    float m_local = -1e30f;
    float sv[4];
#pragma unroll
    for (int r = 0; r < 4; ++r) {
        int t = lane + r * 64;
        float s = -1e30f;
        if (t < count) {
            int j = cols_s[t];
            const unsigned short* kp = qkv + (size_t)j * 768 + DIM + h * HDIM;
            float a = 0.f;
#pragma unroll
            for (int d = 0; d < HDIM; d += 16) {
                uint4 kv0 = *(const uint4*)&kp[d];
                uint4 kv1 = *(const uint4*)&kp[d + 8];
                float4 q0 = *(const float4*)&q_s[wave][d];
                float4 q1 = *(const float4*)&q_s[wave][d + 4];
                float4 q2 = *(const float4*)&q_s[wave][d + 8];
                float4 q3 = *(const float4*)&q_s[wave][d + 12];
                a += q0.x * bl(kv0.x) + q0.y * bh(kv0.x)
                   + q0.z * bl(kv0.y) + q0.w * bh(kv0.y)
                   + q1.x * bl(kv0.z) + q1.y * bh(kv0.z)
                   + q1.z * bl(kv0.w) + q1.w * bh(kv0.w)
                   + q2.x * bl(kv1.x) + q2.y * bh(kv1.x)
                   + q2.z * bl(kv1.y) + q2.w * bh(kv1.y)
                   + q3.x * bl(kv1.z) + q3.y * bh(kv1.z)
                   + q3.z * bl(kv1.w) + q3.w * bh(kv1.w);
            }
            s = a * 0.125f;   // 1/sqrt(64)
        }
        sv[r] = s;
        m_local = fmaxf(m_local, s);
    }
#pragma unroll
    for (int off = 32; off > 0; off >>= 1)
        m_local = fmaxf(m_local, __shfl_xor(m_local, off, 64));

    float sum_local = 0.f;
#pragma unroll
    for (int r = 0; r < 4; ++r) {
        int t = lane + r * 64;
        float e = (t < count) ? expf(sv[r] - m_local) : 0.f;
        sum_local += e;
        sc[wave][t] = e;
    }
#pragma unroll
    for (int off = 32; off > 0; off >>= 1)
        sum_local += __shfl_xor(sum_local, off, 64);
    float inv = 1.0f / sum_local;
    __syncthreads();

    // phase 2: lane = output dim d; batch 4 neighbors for load pipelining
    const unsigned short* vbase = qkv + 2 * DIM + h * HDIM + lane;
    float acc = 0.f;
    int t = 0;
    for (; t + 4 <= count; t += 4) {
        int j0 = cols_s[t], j1 = cols_s[t + 1], j2 = cols_s[t + 2], j3 = cols_s[t + 3];
        float p0 = sc[wave][t], p1 = sc[wave][t + 1], p2 = sc[wave][t + 2], p3 = sc[wave][t + 3];
        float v0 = b2f(vbase[(size_t)j0 * 768]);
        float v1 = b2f(vbase[(size_t)j1 * 768]);
        float v2 = b2f(vbase[(size_t)j2 * 768]);
        float v3 = b2f(vbase[(size_t)j3 * 768]);
        acc += p0 * v0 + p1 * v1 + p2 * v2 + p3 * v3;
    }
    for (; t < count; ++t) {
        int j = cols_s[t];
        acc += sc[wave][t] * b2f(vbase[(size_t)j * 768]);
    }
    ctx[(size_t)i * DIM + h * HDIM + lane] = f2b(acc * inv);
}

// ---------------- LayerNorm ----------------
__global__ __launch_bounds__(256)
void ln_kernel(const float* __restrict__ y, const float* __restrict__ gamma,
               const float* __restrict__ beta, float* __restrict__ out) {
    const int wave = threadIdx.x >> 6;
    const int lane = threadIdx.x & 63;
    const int i = blockIdx.x * 4 + wave;
    float4 v = ((const float4*)(y + (size_t)i * DIM))[lane];
    float s = v.x + v.y + v.z + v.w;
    float ss = v.x * v.x + v.y * v.y + v.z * v.z + v.w * v.w;
#pragma unroll
    for (int off = 32; off > 0; off >>= 1) {
        s += __shfl_xor(s, off, 64);
        ss += __shfl_xor(ss, off, 64);
    }
    float mean = s * (1.f / 256.f);
    float var = ss * (1.f / 256.f) - mean * mean;
    float rstd = rsqrtf(var + 1e-5f);
    float4 g = ((const float4*)gamma)[lane];
    float4 b = ((const float4*)beta)[lane];
    float4 o;
    o.x = (v.x - mean) * rstd * g.x + b.x;
    o.y = (v.y - mean) * rstd * g.y + b.y;
    o.z = (v.z - mean) * rstd * g.z + b.z;
    o.w = (v.w - mean) * rstd * g.w + b.w;
    ((float4*)(out + (size_t)i * DIM))[lane] = o;
}

// ---------------- launch ----------------
extern "C" void kernel_launch(void* const* d_in, const int* in_sizes, int n_in,
                              void* d_out, int out_size, void* d_ws, size_t ws_size,
                              hipStream_t stream) {
    const float* x      = (const float*)d_in[0];
    const int*   eidx   = (const int*)d_in[1];
    const float* w_in   = (const float*)d_in[2];
    const float* b_in   = (const float*)d_in[3];
    const float* w_out  = (const float*)d_in[4];
    const float* b_out  = (const float*)d_in[5];
    const float* w_p    = (const float*)d_in[6];
    const float* b_p    = (const float*)d_in[7];
    const float* gamma  = (const float*)d_in[8];
    const float* beta   = (const float*)d_in[9];
    float* out = (float*)d_out;

    char* ws = (char*)d_ws;
    unsigned int*   mask    = (unsigned int*)(ws + 0);            // 2 MB
    int*            nnz     = (int*)(ws + 2097152);               // 16 KB
    int*            cols    = (int*)(ws + 2113536);               // 4 MB
    unsigned short* qkv_bf  = (unsigned short*)(ws + 6307840);    // 6 MB
    unsigned short* ctx_bf  = (unsigned short*)(ws + 12599296);   // 2 MB
    unsigned short* att_bf  = (unsigned short*)(ws + 14696448);   // 2 MB
    float*          ybuf    = (float*)(ws + 16793600);            // 4 MB
    unsigned short* x_bf    = (unsigned short*)(ws + 20987904);   // 2 MB
    unsigned short* w_in_bf = (unsigned short*)(ws + 23085056);   // 384 KB
    unsigned short* w_out_bf= (unsigned short*)(ws + 23478272);   // 128 KB
    unsigned short* w_p_bf  = (unsigned short*)(ws + 23609344);   // 128 KB

    // conversions to bf16
    f32_to_bf16_kernel<<<(N_NODES * DIM / 4 + 255) / 256, 256, 0, stream>>>(x, x_bf, N_NODES * DIM);
    f32_to_bf16_kernel<<<(768 * DIM / 4 + 255) / 256, 256, 0, stream>>>(w_in, w_in_bf, 768 * DIM);
    f32_to_bf16_kernel<<<(DIM * DIM / 4 + 255) / 256, 256, 0, stream>>>(w_out, w_out_bf, DIM * DIM);
    f32_to_bf16_kernel<<<(DIM * DIM / 4 + 255) / 256, 256, 0, stream>>>(w_p, w_p_bf, DIM * DIM);

    // mask + CSR
    {
        int nwords = N_NODES * MASK_WORDS;
        zero_words_kernel<<<(nwords + 511) / 512, 512, 0, stream>>>(mask, nwords);
        int total = NEDGE + N_NODES;
        build_mask_kernel<<<(total + 255) / 256, 256, 0, stream>>>(eidx, mask);
        extract_csr_kernel<<<N_NODES / 4, 256, 0, stream>>>(mask, nnz, cols);
    }
    // qkv = x @ w_in^T + b_in  -> bf16 [4096 x 768]
    {
        dim3 grid(768 / 128, N_NODES / 128);
        mfma_gemm_bt<true><<<grid, 256, 0, stream>>>(x_bf, w_in_bf, b_in, nullptr,
                                                     qkv_bf, N_NODES, 768, DIM);
    }
    // sparse attention -> ctx bf16 [4096 x 256]
    attn_sparse_kernel<<<N_NODES, 256, 0, stream>>>(qkv_bf, cols, nnz, ctx_bf);
    // att = ctx @ w_out^T + b_out -> bf16
    {
        dim3 grid(DIM / 128, N_NODES / 128);
        mfma_gemm_bt<true><<<grid, 256, 0, stream>>>(ctx_bf, w_out_bf, b_out, nullptr,
                                                     att_bf, N_NODES, DIM, DIM);
    }
    // y = att @ w_p^T + b_p + x -> fp32
    {
        dim3 grid(DIM / 128, N_NODES / 128);
        mfma_gemm_bt<false><<<grid, 256, 0, stream>>>(att_bf, w_p_bf, b_p, x,
                                                      ybuf, N_NODES, DIM, DIM);
    }
    // LayerNorm -> out
    ln_kernel<<<N_NODES / 4, 256, 0, stream>>>(ybuf, gamma, beta, out);
}